// Round 1
// baseline (4036.528 us; speedup 1.0000x reference)
//
#include <hip/hip_runtime.h>
#include <math.h>

#define B_ 128
#define C_ 10
#define R_ 8192
#define I_ 8
#define O_ 16

// Compute u[16] = x[b,r,:] @ W[c,r,:,:] with W streamed as float4.
__device__ __forceinline__ void compute_u(const float* __restrict__ xi,
                                          const float4* __restrict__ wp,
                                          float* __restrict__ u) {
#pragma unroll
    for (int o = 0; o < 16; ++o) u[o] = 0.f;
#pragma unroll
    for (int i = 0; i < 8; ++i) {
        const float xv = xi[i];
        const float4 w0 = wp[i * 4 + 0];
        const float4 w1 = wp[i * 4 + 1];
        const float4 w2 = wp[i * 4 + 2];
        const float4 w3 = wp[i * 4 + 3];
        u[0]  += xv * w0.x; u[1]  += xv * w0.y; u[2]  += xv * w0.z; u[3]  += xv * w0.w;
        u[4]  += xv * w1.x; u[5]  += xv * w1.y; u[6]  += xv * w1.z; u[7]  += xv * w1.w;
        u[8]  += xv * w2.x; u[9]  += xv * w2.y; u[10] += xv * w2.z; u[11] += xv * w2.w;
        u[12] += xv * w3.x; u[13] += xv * w3.y; u[14] += xv * w3.z; u[15] += xv * w3.w;
    }
}

// Logit-denominator pass: D[b,r] = sum_c exp(u_hat[b,c,r,:] . vsum[b,c,:])
__global__ __launch_bounds__(256) void logit_pass(const float* __restrict__ x,
                                                  const float* __restrict__ w,
                                                  const float* __restrict__ vsum,
                                                  float* __restrict__ D) {
    const int b = blockIdx.x;
    const int r = blockIdx.y * 256 + threadIdx.x;

    const float4* xp = (const float4*)(x + ((size_t)b * R_ + r) * I_);
    float4 x0 = xp[0], x1 = xp[1];
    float xi[8] = {x0.x, x0.y, x0.z, x0.w, x1.x, x1.y, x1.z, x1.w};

    float acc = 0.f;
#pragma unroll 1
    for (int c = 0; c < C_; ++c) {
        const float4* wp = (const float4*)(w + ((size_t)c * R_ + r) * (I_ * O_));
        float u[16];
        compute_u(xi, wp, u);
        const float* vs = vsum + ((size_t)b * C_ + c) * O_;
        float l = 0.f;
#pragma unroll
        for (int o = 0; o < 16; ++o) l += u[o] * vs[o];
        acc += __expf(l);
    }
    D[(size_t)b * R_ + r] = acc;
}

// S pass: s[b,c,o] += sum_r c_ij * u_hat[b,c,r,o]
// mode 0: c_ij = 1/C (b_ij == 0).  mode 1: c_ij = exp(u.vsum)/D[b,r]
__global__ __launch_bounds__(256) void s_pass(const float* __restrict__ x,
                                              const float* __restrict__ w,
                                              const float* __restrict__ vsum,
                                              const float* __restrict__ D,
                                              float* __restrict__ s,
                                              int mode) {
    const int b = blockIdx.x;
    const int c = blockIdx.y;
    const int r = blockIdx.z * 256 + threadIdx.x;

    const float4* xp = (const float4*)(x + ((size_t)b * R_ + r) * I_);
    float4 x0 = xp[0], x1 = xp[1];
    float xi[8] = {x0.x, x0.y, x0.z, x0.w, x1.x, x1.y, x1.z, x1.w};

    const float4* wp = (const float4*)(w + ((size_t)c * R_ + r) * (I_ * O_));
    float u[16];
    compute_u(xi, wp, u);

    float cij;
    if (mode == 0) {
        cij = 1.0f / (float)C_;
    } else {
        const float* vs = vsum + ((size_t)b * C_ + c) * O_;
        float l = 0.f;
#pragma unroll
        for (int o = 0; o < 16; ++o) l += u[o] * vs[o];
        cij = __expf(l) / D[(size_t)b * R_ + r];
    }

    // per-thread contribution p[o] = cij * u[o]; reduce over the 256-thread block
    __shared__ float red[4 * 16];
    const int lane = threadIdx.x & 63;
    const int wave = threadIdx.x >> 6;
#pragma unroll
    for (int o = 0; o < 16; ++o) {
        float v = cij * u[o];
        v += __shfl_down(v, 32);
        v += __shfl_down(v, 16);
        v += __shfl_down(v, 8);
        v += __shfl_down(v, 4);
        v += __shfl_down(v, 2);
        v += __shfl_down(v, 1);
        if (lane == 0) red[wave * 16 + o] = v;
    }
    __syncthreads();
    if (threadIdx.x < 16) {
        float v = red[threadIdx.x] + red[16 + threadIdx.x] +
                  red[32 + threadIdx.x] + red[48 + threadIdx.x];
        atomicAdd(&s[((size_t)b * C_ + c) * O_ + threadIdx.x], v);
    }
}

// Squash pass: v = squash(s). mode 0: vsum = v; mode 1: vsum += v; mode 2: out = v
__global__ __launch_bounds__(256) void v_pass(const float* __restrict__ s,
                                              float* __restrict__ vsum,
                                              float* __restrict__ out,
                                              int mode) {
    const int t = blockIdx.x * 256 + threadIdx.x;  // over B*C = 1280
    if (t >= B_ * C_) return;
    float sv[16];
    float sq = 0.f;
#pragma unroll
    for (int o = 0; o < 16; ++o) {
        sv[o] = s[(size_t)t * O_ + o];
        sq += sv[o] * sv[o];
    }
    const float scale = sq / ((1.0f + sq) * sqrtf(sq + 1e-8f));
    if (mode == 0) {
#pragma unroll
        for (int o = 0; o < 16; ++o) vsum[(size_t)t * O_ + o] = scale * sv[o];
    } else if (mode == 1) {
#pragma unroll
        for (int o = 0; o < 16; ++o) vsum[(size_t)t * O_ + o] += scale * sv[o];
    } else {
#pragma unroll
        for (int o = 0; o < 16; ++o) out[(size_t)t * O_ + o] = scale * sv[o];
    }
}

extern "C" void kernel_launch(void* const* d_in, const int* in_sizes, int n_in,
                              void* d_out, int out_size, void* d_ws, size_t ws_size,
                              hipStream_t stream) {
    const float* x = (const float*)d_in[0];        // [B,R,I]
    const float* w = (const float*)d_in[1];        // [C,R,I,O]
    float* out = (float*)d_out;                    // [B,C,O]

    float* s    = (float*)d_ws;                    // B*C*O = 20480 floats
    float* vsum = s + (size_t)B_ * C_ * O_;        // 20480 floats
    float* D    = vsum + (size_t)B_ * C_ * O_;     // B*R = 1048576 floats

    const dim3 sgrid(B_, C_, R_ / 256);
    const dim3 lgrid(B_, R_ / 256);
    const dim3 vgrid((B_ * C_ + 255) / 256);

    // iteration 0: c_ij uniform = 1/C
    hipMemsetAsync(s, 0, (size_t)B_ * C_ * O_ * sizeof(float), stream);
    s_pass<<<sgrid, 256, 0, stream>>>(x, w, nullptr, nullptr, s, 0);
    v_pass<<<vgrid, 256, 0, stream>>>(s, vsum, out, 0);

    // iteration 1
    hipMemsetAsync(s, 0, (size_t)B_ * C_ * O_ * sizeof(float), stream);
    logit_pass<<<lgrid, 256, 0, stream>>>(x, w, vsum, D);
    s_pass<<<sgrid, 256, 0, stream>>>(x, w, vsum, D, s, 1);
    v_pass<<<vgrid, 256, 0, stream>>>(s, vsum, out, 1);

    // iteration 2 (final: write v to out)
    hipMemsetAsync(s, 0, (size_t)B_ * C_ * O_ * sizeof(float), stream);
    logit_pass<<<lgrid, 256, 0, stream>>>(x, w, vsum, D);
    s_pass<<<sgrid, 256, 0, stream>>>(x, w, vsum, D, s, 1);
    v_pass<<<vgrid, 256, 0, stream>>>(s, vsum, out, 2);
}

// Round 2
// 824.256 us; speedup vs baseline: 4.8972x; 4.8972x over previous
//
#include <hip/hip_runtime.h>
#include <math.h>

#define B_ 128
#define C_ 10
#define R_ 8192
#define I_ 8
#define O_ 16

#define RT_S 64   // r-tile per block in s_pass  (LDS W tile = 32 KB)
#define RT_L 8    // r-tile per block in logit_pass (LDS W tile = 4 KB)

// u[a][16], u[b][16] = x_a/x_b (8) @ W (8x16, LDS broadcast)
__device__ __forceinline__ void mat8x16_2(const float* __restrict__ xa,
                                          const float* __restrict__ xb,
                                          const float* __restrict__ wr,
                                          float* __restrict__ ua,
                                          float* __restrict__ ub) {
#pragma unroll
    for (int o = 0; o < 16; ++o) { ua[o] = 0.f; ub[o] = 0.f; }
#pragma unroll
    for (int i = 0; i < 8; ++i) {
        const float a = xa[i], b = xb[i];
#pragma unroll
        for (int q = 0; q < 4; ++q) {
            const float4 wv = ((const float4*)wr)[i * 4 + q];
            ua[q * 4 + 0] += a * wv.x; ua[q * 4 + 1] += a * wv.y;
            ua[q * 4 + 2] += a * wv.z; ua[q * 4 + 3] += a * wv.w;
            ub[q * 4 + 0] += b * wv.x; ub[q * 4 + 1] += b * wv.y;
            ub[q * 4 + 2] += b * wv.z; ub[q * 4 + 3] += b * wv.w;
        }
    }
}

// Drcp[b,r] = 1 / sum_c exp(u_hat[b,c,r,:] . vsum[b,c,:])
// grid: R_/RT_L blocks, 256 threads. Lane handles b={lane, lane+64}; wave handles 2 r's.
__global__ __launch_bounds__(256) void logit_pass(const float* __restrict__ x,
                                                  const float* __restrict__ w,
                                                  const float* __restrict__ vsum,
                                                  float* __restrict__ Drcp) {
    __shared__ float wt[RT_L * 128];  // 4 KB
    const int r0 = blockIdx.x * RT_L;
    const int lane = threadIdx.x & 63;
    const int wave = threadIdx.x >> 6;
    const int b0 = lane, b1 = lane + 64;

    // x[b, r, :] for 2 b x 2 r, held in registers across the c-loop
    float xi[2][2][8];
#pragma unroll
    for (int bb = 0; bb < 2; ++bb) {
        const int b = bb ? b1 : b0;
#pragma unroll
        for (int rr = 0; rr < 2; ++rr) {
            const int r = r0 + wave * 2 + rr;
            const float4* xp = (const float4*)(x + ((size_t)b * R_ + r) * I_);
            const float4 a0 = xp[0], a1 = xp[1];
            xi[bb][rr][0] = a0.x; xi[bb][rr][1] = a0.y; xi[bb][rr][2] = a0.z; xi[bb][rr][3] = a0.w;
            xi[bb][rr][4] = a1.x; xi[bb][rr][5] = a1.y; xi[bb][rr][6] = a1.z; xi[bb][rr][7] = a1.w;
        }
    }

    float dacc[2][2] = {{0.f, 0.f}, {0.f, 0.f}};

#pragma unroll 1
    for (int c = 0; c < C_; ++c) {
        __syncthreads();
        // stage W[c, r0:r0+RT_L, :, :] = 1024 floats = 256 float4, 1 per thread
        const float4* wsrc = (const float4*)(w + ((size_t)c * R_ + r0) * (I_ * O_));
        ((float4*)wt)[threadIdx.x] = wsrc[threadIdx.x];
        __syncthreads();

        float vs0[16], vs1[16];
        {
            const float4* vp0 = (const float4*)(vsum + ((size_t)b0 * C_ + c) * O_);
            const float4* vp1 = (const float4*)(vsum + ((size_t)b1 * C_ + c) * O_);
#pragma unroll
            for (int q = 0; q < 4; ++q) {
                const float4 v0 = vp0[q], v1 = vp1[q];
                vs0[q * 4 + 0] = v0.x; vs0[q * 4 + 1] = v0.y; vs0[q * 4 + 2] = v0.z; vs0[q * 4 + 3] = v0.w;
                vs1[q * 4 + 0] = v1.x; vs1[q * 4 + 1] = v1.y; vs1[q * 4 + 2] = v1.z; vs1[q * 4 + 3] = v1.w;
            }
        }

#pragma unroll
        for (int rr = 0; rr < 2; ++rr) {
            const float* wr = wt + (wave * 2 + rr) * 128;
            float u0[16], u1[16];
            mat8x16_2(xi[0][rr], xi[1][rr], wr, u0, u1);
            float l0 = 0.f, l1 = 0.f;
#pragma unroll
            for (int o = 0; o < 16; ++o) { l0 += u0[o] * vs0[o]; l1 += u1[o] * vs1[o]; }
            dacc[0][rr] += __expf(l0);
            dacc[1][rr] += __expf(l1);
        }
    }

#pragma unroll
    for (int bb = 0; bb < 2; ++bb) {
        const int b = bb ? b1 : b0;
#pragma unroll
        for (int rr = 0; rr < 2; ++rr) {
            const int r = r0 + wave * 2 + rr;
            Drcp[(size_t)b * R_ + r] = 1.0f / dacc[bb][rr];
        }
    }
}

// s[b,c,o] += sum_{r in tile} c_ij * u_hat[b,c,r,o]
// grid: (R_/RT_S, C_). Lane handles b={lane, lane+64}; wave handles 16 contiguous r's.
__global__ __launch_bounds__(256) void s_pass(const float* __restrict__ x,
                                              const float* __restrict__ w,
                                              const float* __restrict__ vsum,
                                              const float* __restrict__ Drcp,
                                              float* __restrict__ s,
                                              int mode) {
    __shared__ float wt[RT_S * 128];  // 32 KB, reused as reduce buffer
    const int c = blockIdx.y;
    const int r0 = blockIdx.x * RT_S;
    const int lane = threadIdx.x & 63;
    const int wave = threadIdx.x >> 6;
    const int b0 = lane, b1 = lane + 64;

    // stage W[c, r0:r0+RT_S, :, :] = 8192 floats = 2048 float4, 8 per thread
    {
        const float4* wsrc = (const float4*)(w + ((size_t)c * R_ + r0) * (I_ * O_));
#pragma unroll
        for (int k = 0; k < 8; ++k)
            ((float4*)wt)[k * 256 + threadIdx.x] = wsrc[k * 256 + threadIdx.x];
    }

    float vs0[16], vs1[16];
    if (mode) {
        const float4* vp0 = (const float4*)(vsum + ((size_t)b0 * C_ + c) * O_);
        const float4* vp1 = (const float4*)(vsum + ((size_t)b1 * C_ + c) * O_);
#pragma unroll
        for (int q = 0; q < 4; ++q) {
            const float4 v0 = vp0[q], v1 = vp1[q];
            vs0[q * 4 + 0] = v0.x; vs0[q * 4 + 1] = v0.y; vs0[q * 4 + 2] = v0.z; vs0[q * 4 + 3] = v0.w;
            vs1[q * 4 + 0] = v1.x; vs1[q * 4 + 1] = v1.y; vs1[q * 4 + 2] = v1.z; vs1[q * 4 + 3] = v1.w;
        }
    }
    __syncthreads();

    float acc0[16], acc1[16];
#pragma unroll
    for (int o = 0; o < 16; ++o) { acc0[o] = 0.f; acc1[o] = 0.f; }

#pragma unroll 1
    for (int rr = 0; rr < 16; ++rr) {
        const int rl = wave * 16 + rr;
        const int r = r0 + rl;

        float xa[8], xb[8];
        {
            const float4* xp0 = (const float4*)(x + ((size_t)b0 * R_ + r) * I_);
            const float4* xp1 = (const float4*)(x + ((size_t)b1 * R_ + r) * I_);
            const float4 a0 = xp0[0], a1 = xp0[1], b0v = xp1[0], b1v = xp1[1];
            xa[0] = a0.x; xa[1] = a0.y; xa[2] = a0.z; xa[3] = a0.w;
            xa[4] = a1.x; xa[5] = a1.y; xa[6] = a1.z; xa[7] = a1.w;
            xb[0] = b0v.x; xb[1] = b0v.y; xb[2] = b0v.z; xb[3] = b0v.w;
            xb[4] = b1v.x; xb[5] = b1v.y; xb[6] = b1v.z; xb[7] = b1v.w;
        }

        const float* wr = wt + rl * 128;
        float u0[16], u1[16];
        mat8x16_2(xa, xb, wr, u0, u1);

        float c0, c1;
        if (mode == 0) {
            c0 = c1 = 1.0f / (float)C_;
        } else {
            float l0 = 0.f, l1 = 0.f;
#pragma unroll
            for (int o = 0; o < 16; ++o) { l0 += u0[o] * vs0[o]; l1 += u1[o] * vs1[o]; }
            c0 = __expf(l0) * Drcp[(size_t)b0 * R_ + r];
            c1 = __expf(l1) * Drcp[(size_t)b1 * R_ + r];
        }
#pragma unroll
        for (int o = 0; o < 16; ++o) { acc0[o] += c0 * u0[o]; acc1[o] += c1 * u1[o]; }
    }

    // block reduce: reuse wt as red[4][128][16]
    __syncthreads();
    float* red = wt;
#pragma unroll
    for (int q = 0; q < 4; ++q) {
        float4 v0 = make_float4(acc0[q * 4 + 0], acc0[q * 4 + 1], acc0[q * 4 + 2], acc0[q * 4 + 3]);
        float4 v1 = make_float4(acc1[q * 4 + 0], acc1[q * 4 + 1], acc1[q * 4 + 2], acc1[q * 4 + 3]);
        ((float4*)(red + wave * 2048 + b0 * 16))[q] = v0;
        ((float4*)(red + wave * 2048 + b1 * 16))[q] = v1;
    }
    __syncthreads();
#pragma unroll
    for (int k = 0; k < 8; ++k) {
        const int idx = threadIdx.x * 8 + k;
        const float v = red[idx] + red[2048 + idx] + red[4096 + idx] + red[6144 + idx];
        const int b = idx >> 4, o = idx & 15;
        atomicAdd(&s[((size_t)b * C_ + c) * O_ + o], v);
    }
}

// Squash: v = squash(s). mode 0: vsum = v; mode 1: vsum += v; mode 2: out = v
__global__ __launch_bounds__(256) void v_pass(const float* __restrict__ s,
                                              float* __restrict__ vsum,
                                              float* __restrict__ out,
                                              int mode) {
    const int t = blockIdx.x * 256 + threadIdx.x;  // over B*C = 1280
    if (t >= B_ * C_) return;
    float sv[16];
    float sq = 0.f;
#pragma unroll
    for (int o = 0; o < 16; ++o) {
        sv[o] = s[(size_t)t * O_ + o];
        sq += sv[o] * sv[o];
    }
    const float scale = sq / ((1.0f + sq) * sqrtf(sq + 1e-8f));
    if (mode == 0) {
#pragma unroll
        for (int o = 0; o < 16; ++o) vsum[(size_t)t * O_ + o] = scale * sv[o];
    } else if (mode == 1) {
#pragma unroll
        for (int o = 0; o < 16; ++o) vsum[(size_t)t * O_ + o] += scale * sv[o];
    } else {
#pragma unroll
        for (int o = 0; o < 16; ++o) out[(size_t)t * O_ + o] = scale * sv[o];
    }
}

extern "C" void kernel_launch(void* const* d_in, const int* in_sizes, int n_in,
                              void* d_out, int out_size, void* d_ws, size_t ws_size,
                              hipStream_t stream) {
    const float* x = (const float*)d_in[0];        // [B,R,I]
    const float* w = (const float*)d_in[1];        // [C,R,I,O]
    float* out = (float*)d_out;                    // [B,C,O]

    float* s    = (float*)d_ws;                    // 20480 floats
    float* vsum = s + (size_t)B_ * C_ * O_;        // 20480 floats
    float* Drcp = vsum + (size_t)B_ * C_ * O_;     // B*R = 1048576 floats

    const dim3 sgrid(R_ / RT_S, C_);   // (128, 10)
    const dim3 lgrid(R_ / RT_L);       // 1024
    const dim3 vgrid((B_ * C_ + 255) / 256);

    // iteration 0: c_ij uniform = 1/C
    hipMemsetAsync(s, 0, (size_t)B_ * C_ * O_ * sizeof(float), stream);
    s_pass<<<sgrid, 256, 0, stream>>>(x, w, nullptr, nullptr, s, 0);
    v_pass<<<vgrid, 256, 0, stream>>>(s, vsum, out, 0);

    // iteration 1
    hipMemsetAsync(s, 0, (size_t)B_ * C_ * O_ * sizeof(float), stream);
    logit_pass<<<lgrid, 256, 0, stream>>>(x, w, vsum, Drcp);
    s_pass<<<sgrid, 256, 0, stream>>>(x, w, vsum, Drcp, s, 1);
    v_pass<<<vgrid, 256, 0, stream>>>(s, vsum, out, 1);

    // iteration 2 (final: write v to out)
    hipMemsetAsync(s, 0, (size_t)B_ * C_ * O_ * sizeof(float), stream);
    logit_pass<<<lgrid, 256, 0, stream>>>(x, w, vsum, Drcp);
    s_pass<<<sgrid, 256, 0, stream>>>(x, w, vsum, Drcp, s, 1);
    v_pass<<<vgrid, 256, 0, stream>>>(s, vsum, out, 2);
}